// Round 9
// baseline (80.665 us; speedup 1.0000x reference)
//
#include <hip/hip_runtime.h>

// Discrete color pick via fp32 sign tests: predicates must match numpy fp32
// rounding bit-exactly. contract(off) keeps exact paths exact (also prevents
// mul+add fusing inside the exact circle test). Screens decide by sign and
// flag a band around zero; band hit -> bit-exact 4-cell fallback.
//
// r9: VALU-bound fix (r6/r8 both ~21us == 415 slots/thread x 2cyc model).
// PPT=2 points are packed into <2 x float> so the float pipeline lowers to
// full-rate VOP3P v_pk_{fma,add,mul,min,max}_f32, ~halving packable float
// ops. Packed IEEE per-component == scalar, so exactness arguments survive.
// Circle test switched to EXACT (mul,mul,add = numpy order) - no band needed.
#pragma clang fp contract(off)

#define NPTS 2097152
#define PPT  2
#define NTHREADS (NPTS / PPT)   // 1048576

typedef float v2f __attribute__((ext_vector_type(2)));
#define V2(a, b)      ((v2f){(a), (b)})
#define FMA2(a, b, c) __builtin_elementwise_fma((a), (b), (c))
#define MIN2(a, b)    __builtin_elementwise_min((a), (b))
#define MAX2(a, b)    __builtin_elementwise_max((a), (b))

// LDS float layout:
//   CELLS [49][20]: padded 7x7 grid, 16 payload floats + 4 pad (80 B stride)
//     [0..8]  tri affine: d0y,-d0x,k0, d1y,-d1x,k1, d2y,-d2x,k2  (k fp64->fp32)
//     [9..11] circle: ocx,ocy,r2(=fl(orr*orr))
//     [12..15] ellipse: ecx,ecy,1/erx,1/ery
//   COLS [76][4]: shape colors, entry 75 = black (no-hit)
#define L_COL  980
#define LDS_FLOATS (980 + 304)   // 5136 B

// Bands (sign-decide + band-flag; band hit => bit-exact fallback):
//   tri affine vs numpy |delta| <= ~1.1e-7  -> 1e-6 (9x margin)
//   ell recip  vs numpy |delta| <= ~6e-7    -> 1e-5 (validated r1-r8, absmax 0)
//   circle: EXACT, no band.
#define EPS_T 1e-6f
#define EPS_E 1e-5f

// Bit-exact numpy-order evaluation over the 4 candidate cells, reading raw
// params (fl(by-ay) etc. reproduce numpy's fp32 ops exactly). Non-candidate
// shapes are >= 5e-4 away geometrically vs fp sign-test reach ~3e-7, so the
// 4-cell restriction is exact for numpy arithmetic too. Rare (~1e-3 of pts).
__device__ __noinline__ int exact_point(float px, float py, int ih, int jh,
                                        const float* __restrict__ p) {
    int idx = -1;
#pragma clang loop unroll(disable)
    for (int s = 0; s < 4; ++s) {
        int ii = ih - 1 + (s >> 1), jj = jh - 1 + (s & 1);   // ascending cell
        if ((unsigned)ii > 4u || (unsigned)jj > 4u) continue;
        int c = 5 * ii + jj;
        const float* cell = p + 28 * c;
        float ax = cell[1], ay = cell[2], bx = cell[3], by = cell[4], cx = cell[5], cy = cell[6];
        float e0 = (px - ax) * (by - ay) - (py - ay) * (bx - ax);
        float e1 = (px - bx) * (cy - by) - (py - by) * (cx - bx);
        float e2 = (px - cx) * (ay - cy) - (py - cy) * (ax - cx);
        bool tin = (e0 >= 0.f && e1 >= 0.f && e2 >= 0.f) ||
                   (e0 <= 0.f && e1 <= 0.f && e2 <= 0.f);
        if (tin) idx = 3 * c;
        float dx = px - cell[12], dy = py - cell[13];
        if (dx * dx + dy * dy <= cell[14] * cell[14]) idx = 3 * c + 1;
        float u = (px - cell[20]) / cell[22];   // IEEE division, numpy order
        float v = (py - cell[21]) / cell[23];
        if (u * u + v * v <= 1.0f) idx = 3 * c + 2;
    }
    return idx;
}

__global__ __launch_bounds__(256) void vg_fused(const float* __restrict__ x,
                                                const float* __restrict__ p,
                                                float* __restrict__ out) {
    __shared__ float lds[LDS_FLOATS];
    int tl = threadIdx.x;
    int t  = blockIdx.x * 256 + tl;

    // ---- build padded packed cell table (threads 0..48) ----
    if (tl < 49) {
        int gi = tl / 7, gj = tl % 7;
        float* o = lds + tl * 20;
        if (gi >= 1 && gi <= 5 && gj >= 1 && gj <= 5) {
            int c = (gi - 1) * 5 + (gj - 1);
            const float* cell = p + c * 28;
            float ax = cell[1], ay = cell[2], bx = cell[3], by = cell[4], cx = cell[5], cy = cell[6];
            float d0y = by - ay, d0x = bx - ax;   // numpy-rounded diffs
            float d1y = cy - by, d1x = cx - bx;
            float d2y = ay - cy, d2x = ax - cx;
            o[0] = d0y; o[1] = -d0x; o[2] = (float)((double)ay * (double)d0x - (double)ax * (double)d0y);
            o[3] = d1y; o[4] = -d1x; o[5] = (float)((double)by * (double)d1x - (double)bx * (double)d1y);
            o[6] = d2y; o[7] = -d2x; o[8] = (float)((double)cy * (double)d2x - (double)cx * (double)d2y);
            o[9]  = cell[12]; o[10] = cell[13]; o[11] = cell[14] * cell[14];
            o[12] = cell[20]; o[13] = cell[21]; o[14] = 1.0f / cell[22]; o[15] = 1.0f / cell[23];
        } else {
            // dummy border cell: all three tests false, never within any band
            o[0] = 0.f; o[1] = 0.f; o[2] = 10.f;    // e0 = +10
            o[3] = 0.f; o[4] = 0.f; o[5] = -10.f;   // e1 = -10 -> mixed signs
            o[6] = 0.f; o[7] = 0.f; o[8] = 0.f;
            o[9] = 0.f; o[10] = 0.f; o[11] = -10.f; // tc >= 0 > r2
            o[12] = 1000.f; o[13] = 1000.f; o[14] = 1.f; o[15] = 1.f;  // te ~ 1e6
        }
        o[16] = 0.f; o[17] = 0.f; o[18] = 0.f; o[19] = 0.f;
    }
    // ---- build color table (threads 128..203 -> entries 0..75) ----
    if (tl >= 128 && tl < 204) {
        int e = tl - 128;
        float* col = lds + L_COL + e * 4;
        if (e < 75) {
            int c = e / 3, kind = e - 3 * c;
            const float* cell = p + c * 28;
            int base = (kind == 0) ? 8 : (kind == 1) ? 16 : 25;
            col[0] = cell[base]; col[1] = cell[base + 1]; col[2] = cell[base + 2];
        } else {
            col[0] = 0.f; col[1] = 0.f; col[2] = 0.f;   // no-hit -> black
        }
        col[3] = 0.f;
    }
    __syncthreads();

    // ---- load 2 points (one contiguous float4 per lane, coalesced) ----
    float4 xv = ((const float4*)x)[t];
    v2f X = V2(xv.x, xv.z);
    v2f Y = V2(xv.y, xv.w);

    // padded candidate block {ih,ih+1}x{jh,jh+1}; ih = floor(5X+0.4025) in
    // [0,5] (reach 0.0805 >= 0.08 shape reach + fp slack; r4-r8 proven)
    int ih0 = (int)floorf(__builtin_fmaf(X.x, 5.0f, 0.4025f));
    int jh0 = (int)floorf(__builtin_fmaf(Y.x, 5.0f, 0.4025f));
    int ih1 = (int)floorf(__builtin_fmaf(X.y, 5.0f, 0.4025f));
    int jh1 = (int)floorf(__builtin_fmaf(Y.y, 5.0f, 0.4025f));
    const float* base0 = lds + (7 * ih0 + jh0) * 20;
    const float* base1 = lds + (7 * ih1 + jh1) * 20;
    int sb0 = 15 * ih0 + 3 * jh0 - 18;   // sid = sb + {0,3,15,18}[s]
    int sb1 = 15 * ih1 + 3 * jh1 - 18;

    int idx0 = -1, idx1 = -1;
    bool unc0 = false, unc1 = false;
    const int foff[4] = {0, 20, 140, 160};   // float offsets of the 4 cells
    const int soff[4] = {0, 3, 15, 18};      // sid offsets (ascending cell)

#pragma unroll
    for (int s = 0; s < 4; ++s) {
        // 8 independent ds_read_b128 (4 per point), immediate offsets
        const float4* ca = (const float4*)(base0 + foff[s]);
        const float4* cb = (const float4*)(base1 + foff[s]);
        float4 a0 = ca[0], a1 = ca[1], a2 = ca[2], a3 = ca[3];
        float4 b0 = cb[0], b1 = cb[1], b2 = cb[2], b3 = cb[3];
        int sid0 = sb0 + soff[s], sid1 = sb1 + soff[s];

        // ---- triangle: affine screen (packed fma), sign-decide + band ----
        v2f e0 = FMA2(X, V2(a0.x, b0.x), FMA2(Y, V2(a0.y, b0.y), V2(a0.z, b0.z)));
        v2f e1 = FMA2(X, V2(a0.w, b0.w), FMA2(Y, V2(a1.x, b1.x), V2(a1.y, b1.y)));
        v2f e2 = FMA2(X, V2(a1.z, b1.z), FMA2(Y, V2(a1.w, b1.w), V2(a2.x, b2.x)));
        v2f lo = MIN2(MIN2(e0, e1), e2);
        v2f hi = MAX2(MAX2(e0, e1), e2);

        // ---- circle: EXACT numpy order (pk mul,mul,add; contract off) ----
        v2f dx = X - V2(a2.y, b2.y);
        v2f dy = Y - V2(a2.z, b2.z);
        v2f tc = dx * dx + dy * dy;

        // ---- ellipse: reciprocal screen (packed), sign-decide + band ----
        v2f ex = X - V2(a3.x, b3.x);
        v2f ey = Y - V2(a3.y, b3.y);
        v2f u  = ex * V2(a3.z, b3.z);
        v2f v  = ey * V2(a3.w, b3.w);
        v2f te = FMA2(u, u, v * v);
        v2f tm = te - V2(1.0f, 1.0f);

        // ---- scalar decisions, point 0 ----
        {
            bool ts = (lo.x >= 0.0f) | (hi.x <= 0.0f);
            unc0 |= (__builtin_fabsf(lo.x) < EPS_T) | (__builtin_fabsf(hi.x) < EPS_T);
            idx0 = ts ? sid0 : idx0;
            idx0 = (tc.x <= a2.w) ? sid0 + 1 : idx0;          // exact circle
            unc0 |= (__builtin_fabsf(tm.x) < EPS_E);
            idx0 = (te.x <= 1.0f) ? sid0 + 2 : idx0;
        }
        // ---- scalar decisions, point 1 ----
        {
            bool ts = (lo.y >= 0.0f) | (hi.y <= 0.0f);
            unc1 |= (__builtin_fabsf(lo.y) < EPS_T) | (__builtin_fabsf(hi.y) < EPS_T);
            idx1 = ts ? sid1 : idx1;
            idx1 = (tc.y <= b2.w) ? sid1 + 1 : idx1;          // exact circle
            unc1 |= (__builtin_fabsf(tm.y) < EPS_E);
            idx1 = (te.y <= 1.0f) ? sid1 + 2 : idx1;
        }
    }

    // rare bit-exact fallback for band-flagged points
    if (__builtin_expect(unc0, 0)) idx0 = exact_point(X.x, Y.x, ih0, jh0, p);
    if (__builtin_expect(unc1, 0)) idx1 = exact_point(X.y, Y.y, ih1, jh1, p);

    // color gather from LDS (entry 75 = black) + coalesced 8B stores
    const float4* col4 = (const float4*)(lds + L_COL);
    float4 c0 = col4[idx0 < 0 ? 75 : idx0];
    float4 c1 = col4[idx1 < 0 ? 75 : idx1];

    float2* o2 = (float2*)out;
    o2[3 * t + 0] = make_float2(c0.x, c0.y);
    o2[3 * t + 1] = make_float2(c0.z, c1.x);
    o2[3 * t + 2] = make_float2(c1.y, c1.z);
}

extern "C" void kernel_launch(void* const* d_in, const int* in_sizes, int n_in,
                              void* d_out, int out_size, void* d_ws, size_t ws_size,
                              hipStream_t stream) {
    const float* x = (const float*)d_in[0];   // (NPTS, 2) fp32
    const float* p = (const float*)d_in[1];   // (700,)   fp32
    float* out = (float*)d_out;               // (NPTS, 3) fp32
    (void)d_ws; (void)ws_size;

    vg_fused<<<NTHREADS / 256, 256, 0, stream>>>(x, p, out);
}

// Round 10
// 78.835 us; speedup vs baseline: 1.0232x; 1.0232x over previous
//
#include <hip/hip_runtime.h>

// Discrete color pick via fp32 sign tests: predicates must match numpy fp32
// rounding bit-exactly. contract(off) keeps every exact path exact (tri edge
// functions and circle MUST stay mul,mul,sub/add - no fma fusion).
//
// r10: DS-byte cut (r6/r8/r9 all ~21us kernel == LDS gather conflict model:
// ~22 unique 16B windows / 8 positions -> ~3-deep conflicts -> ~19cyc/b128).
// Triangle switched to the EXACT 6-float vertex form (in-kernel fl(by-ay)
// reproduces numpy bit-exactly) -> payload 16 -> 13 floats/cell, SoA as
// 3x[49]float4 + 1x[49]b32, all 16B-aligned, one index reg + imm offsets.
// Gather traffic -23%. Tri/circle exact => fallback only via ellipse band.
#pragma clang fp contract(off)

#define NPTS 2097152
#define PPT  2
#define NTHREADS (NPTS / PPT)   // 1048576

// LDS float layout (padded 7x7 grid, row-major ci = 7*gi+gj):
//   L_A [49][4]: ax,ay,bx,by      (floats 0..195,   byte off 0)
//   L_B [49][4]: cx,cy,ocx,ocy    (floats 196..391, byte off  784)
//   L_C [49][4]: r,ecx,ecy,1/erx  (floats 392..587, byte off 1568)
//   L_D [49][4]: 1/ery,pad,pad,pad(floats 588..783, byte off 2352; read .x b32)
//   L_COL [76][4]: colors, entry 75 = black
#define L_B    196
#define L_C    392
#define L_D    588
#define L_COL  784
#define LDS_FLOATS (784 + 304)   // 4352 B

// Ellipse screen band (only remaining screen): recip-mul + fma-reassoc vs
// numpy div-mul-add |delta| <= ~6e-7 on te~1 -> 1e-5 (validated r1-r9,
// absmax 0.0 every round). Tri and circle are evaluated EXACTLY inline.
#define EPS_E 1e-5f

// Bit-exact numpy-order evaluation over the 4 candidate cells, reading raw
// params (fl(by-ay) etc. reproduce numpy's fp32 ops exactly). Non-candidate
// shapes are >= 5e-4 away geometrically vs fp sign-test reach ~3e-7, so the
// 4-cell restriction is exact for numpy arithmetic too. Rare (~1e-3 of pts,
// ellipse band only).
__device__ __noinline__ int exact_point(float px, float py, int ih, int jh,
                                        const float* __restrict__ p) {
    int idx = -1;
#pragma clang loop unroll(disable)
    for (int s = 0; s < 4; ++s) {
        int ii = ih - 1 + (s >> 1), jj = jh - 1 + (s & 1);   // ascending cell
        if ((unsigned)ii > 4u || (unsigned)jj > 4u) continue;
        int c = 5 * ii + jj;
        const float* cell = p + 28 * c;
        float ax = cell[1], ay = cell[2], bx = cell[3], by = cell[4], cx = cell[5], cy = cell[6];
        float e0 = (px - ax) * (by - ay) - (py - ay) * (bx - ax);
        float e1 = (px - bx) * (cy - by) - (py - by) * (cx - bx);
        float e2 = (px - cx) * (ay - cy) - (py - cy) * (ax - cx);
        bool tin = (e0 >= 0.f && e1 >= 0.f && e2 >= 0.f) ||
                   (e0 <= 0.f && e1 <= 0.f && e2 <= 0.f);
        if (tin) idx = 3 * c;
        float dx = px - cell[12], dy = py - cell[13];
        if (dx * dx + dy * dy <= cell[14] * cell[14]) idx = 3 * c + 1;
        float u = (px - cell[20]) / cell[22];   // IEEE division, numpy order
        float v = (py - cell[21]) / cell[23];
        if (u * u + v * v <= 1.0f) idx = 3 * c + 2;
    }
    return idx;
}

__global__ __launch_bounds__(256) void vg_fused(const float* __restrict__ x,
                                                const float* __restrict__ p,
                                                float* __restrict__ out) {
    __shared__ float lds[LDS_FLOATS];
    int tl = threadIdx.x;
    int t  = blockIdx.x * 256 + tl;

    // ---- build padded SoA cell tables (threads 0..48) ----
    if (tl < 49) {
        int gi = tl / 7, gj = tl % 7;
        float4* A = (float4*)lds;
        float4* B = (float4*)(lds + L_B);
        float4* C = (float4*)(lds + L_C);
        float4* D = (float4*)(lds + L_D);
        if (gi >= 1 && gi <= 5 && gj >= 1 && gj <= 5) {
            int c = (gi - 1) * 5 + (gj - 1);
            const float* cell = p + c * 28;
            A[tl] = make_float4(cell[1], cell[2], cell[3], cell[4]);    // ax,ay,bx,by
            B[tl] = make_float4(cell[5], cell[6], cell[12], cell[13]);  // cx,cy,ocx,ocy
            C[tl] = make_float4(cell[14], cell[20], cell[21], 1.0f / cell[22]); // r,ecx,ecy,irx
            D[tl] = make_float4(1.0f / cell[23], 0.f, 0.f, 0.f);        // iry
        } else {
            // dummy border cell: tri edges strictly mixed-sign for any point
            // in [0,1]^2 (e0<=-2, e1>=+2); circle/ellipse centers far away.
            A[tl] = make_float4(0.f, -2.f, 1.f, -2.f);
            B[tl] = make_float4(0.f, -3.f, 50.f, 50.f);
            C[tl] = make_float4(0.f, 50.f, 50.f, 1.f);
            D[tl] = make_float4(1.f, 0.f, 0.f, 0.f);
        }
    }
    // ---- build color table (threads 128..203 -> entries 0..75) ----
    if (tl >= 128 && tl < 204) {
        int e = tl - 128;
        float* col = lds + L_COL + e * 4;
        if (e < 75) {
            int c = e / 3, kind = e - 3 * c;
            const float* cell = p + c * 28;
            int base = (kind == 0) ? 8 : (kind == 1) ? 16 : 25;
            col[0] = cell[base]; col[1] = cell[base + 1]; col[2] = cell[base + 2];
        } else {
            col[0] = 0.f; col[1] = 0.f; col[2] = 0.f;   // no-hit -> black
        }
        col[3] = 0.f;
    }
    __syncthreads();

    // ---- load 2 points (one contiguous float4 per lane, coalesced) ----
    float4 xv = ((const float4*)x)[t];
    float PX[PPT] = {xv.x, xv.z};
    float PY[PPT] = {xv.y, xv.w};
    int idx[PPT], ih[PPT], jh[PPT], sb[PPT], cb[PPT];
    bool unc[PPT];

#pragma unroll
    for (int k = 0; k < PPT; ++k) {
        // padded candidate block {ih,ih+1}x{jh,jh+1}; ih = floor(5X+0.4025)
        // in [0,5] (reach 0.0805 >= 0.08 shape reach + fp slack; r4-r9 proven)
        ih[k] = (int)floorf(__builtin_fmaf(PX[k], 5.0f, 0.4025f));
        jh[k] = (int)floorf(__builtin_fmaf(PY[k], 5.0f, 0.4025f));
        cb[k] = 7 * ih[k] + jh[k];          // ci = cb + {0,1,7,8}
        sb[k] = 15 * ih[k] + 3 * jh[k] - 18; // sid = sb + {0,3,15,18}
        idx[k] = -1; unc[k] = false;
    }

    const float4* LA = (const float4*)lds;
    const float4* LB = (const float4*)(lds + L_B);
    const float4* LC = (const float4*)(lds + L_C);
    const int coff[4] = {0, 1, 7, 8};
    const int soff[4] = {0, 3, 15, 18};

#pragma unroll
    for (int k = 0; k < PPT; ++k) {
        float X = PX[k], Y = PY[k];
#pragma unroll
        for (int s = 0; s < 4; ++s) {
            int ci = cb[k] + coff[s];
            // 3 b128 + 1 b32, one index, immediate offsets 0/784/1568/2352
            float4 A = LA[ci];
            float4 B = LB[ci];
            float4 C = LC[ci];
            float iry = lds[L_D + 4 * ci];
            int sid = sb[k] + soff[s];

            // ---- triangle: EXACT numpy fp32 (d's are the same fl() numpy
            // computes; mul,mul,sub under contract(off)) ----
            float d0y = A.w - A.y, d0x = A.z - A.x;   // by-ay, bx-ax
            float d1y = B.y - A.w, d1x = B.x - A.z;   // cy-by, cx-bx
            float d2y = A.y - B.y, d2x = A.x - B.x;   // ay-cy, ax-cx
            float e0 = (X - A.x) * d0y - (Y - A.y) * d0x;
            float e1 = (X - A.z) * d1y - (Y - A.w) * d1x;
            float e2 = (X - B.x) * d2y - (Y - B.y) * d2x;
            bool tin = (e0 >= 0.f && e1 >= 0.f && e2 >= 0.f) ||
                       (e0 <= 0.f && e1 <= 0.f && e2 <= 0.f);
            idx[k] = tin ? sid : idx[k];

            // ---- circle: EXACT numpy fp32 (r2 = fl(r*r); mul,mul,add) ----
            float r2 = C.x * C.x;
            float dx = X - B.z, dy = Y - B.w;
            float tc = dx * dx + dy * dy;
            idx[k] = (tc <= r2) ? sid + 1 : idx[k];

            // ---- ellipse: reciprocal screen + band -> bit-exact fallback ----
            float ex = X - C.y, ey = Y - C.z;
            float u = ex * C.w, v = ey * iry;
            float te = __builtin_fmaf(u, u, v * v);
            unc[k] = unc[k] | (__builtin_fabsf(te - 1.0f) < EPS_E);
            idx[k] = (te <= 1.0f) ? sid + 2 : idx[k];
        }
    }

    // rare bit-exact fallback (ellipse band only)
#pragma unroll
    for (int k = 0; k < PPT; ++k)
        if (__builtin_expect(unc[k], 0))
            idx[k] = exact_point(PX[k], PY[k], ih[k], jh[k], p);

    // color gather from LDS (entry 75 = black) + coalesced 8B stores
    const float4* col4 = (const float4*)(lds + L_COL);
    float4 c0 = col4[idx[0] < 0 ? 75 : idx[0]];
    float4 c1 = col4[idx[1] < 0 ? 75 : idx[1]];

    float2* o2 = (float2*)out;
    o2[3 * t + 0] = make_float2(c0.x, c0.y);
    o2[3 * t + 1] = make_float2(c0.z, c1.x);
    o2[3 * t + 2] = make_float2(c1.y, c1.z);
}

extern "C" void kernel_launch(void* const* d_in, const int* in_sizes, int n_in,
                              void* d_out, int out_size, void* d_ws, size_t ws_size,
                              hipStream_t stream) {
    const float* x = (const float*)d_in[0];   // (NPTS, 2) fp32
    const float* p = (const float*)d_in[1];   // (700,)   fp32
    float* out = (float*)d_out;               // (NPTS, 3) fp32
    (void)d_ws; (void)ws_size;

    vg_fused<<<NTHREADS / 256, 256, 0, stream>>>(x, p, out);
}